// Round 3
// baseline (354.482 us; speedup 1.0000x reference)
//
#include <hip/hip_runtime.h>
#include <hip/hip_bf16.h>
#include <math.h>

#define NF 128

typedef short bf16x8 __attribute__((ext_vector_type(8)));
typedef float f32x4  __attribute__((ext_vector_type(4)));

union U8 { unsigned u[4]; bf16x8 v; };

__device__ __forceinline__ unsigned pk2(float lo, float hi) {
    union { __hip_bfloat162 h2; unsigned u; } c;
    c.h2 = __float22bfloat162_rn(make_float2(lo, hi));
    return c.u;    // low 16 bits = lo
}
__device__ __forceinline__ unsigned short f2bf(float f) {
    union { __hip_bfloat16 h; unsigned short u; } c;
    c.h = __float2bfloat16(f);
    return c.u;
}

// ---------------- K0: per-segment start/count ----------------
__global__ void k_segtab(const int* __restrict__ ptr, const int* __restrict__ split,
                         int nseg, int* __restrict__ segstart, int* __restrict__ segcnt) {
    int s = blockIdx.x * blockDim.x + threadIdx.x;
    if (s >= nseg) return;
    int g = s >> 1;
    int base = ptr[g];
    int sp = split[g];
    segstart[s] = (s & 1) ? base + sp : base;
    segcnt[s]   = (s & 1) ? (ptr[g + 1] - base - sp) : sp;
}

// ---------------- K1: per-node (seg,loc) ----------------
__global__ void k_node(const int* __restrict__ ptr, const int* __restrict__ split,
                       int nB, int N, unsigned* __restrict__ segloc) {
    int i = blockIdx.x * blockDim.x + threadIdx.x;
    if (i >= N) return;
    int lo = 0, hi = nB + 1;
    while (lo < hi) { int mid = (lo + hi) >> 1; if (ptr[mid] <= i) lo = mid + 1; else hi = mid; }
    int g = lo - 1;
    int local = i - ptr[g];
    int sp = split[g];
    int drug = (local >= sp) ? 1 : 0;
    int seg = 2 * g + drug;
    int loc = local - (drug ? sp : 0);
    segloc[i] = ((unsigned)seg << 8) | (unsigned)loc;
}

// ---------------- K2: edge pack + segment histogram ----------------
__global__ void k_hist(const int* __restrict__ src, const int* __restrict__ dst, int E,
                       const unsigned* __restrict__ segloc,
                       unsigned* __restrict__ epack, int* __restrict__ hist) {
    int e = blockIdx.x * blockDim.x + threadIdx.x;
    if (e >= E) return;
    unsigned ss = segloc[src[e]], dd = segloc[dst[e]];
    unsigned seg = ss >> 8;
    if (seg == (dd >> 8)) {
        epack[e] = (seg << 12) | ((dd & 63u) << 6) | (ss & 63u);
        atomicAdd(&hist[seg], 1);
    } else {
        epack[e] = 0xFFFFFFFFu;
    }
}

// ---------------- K3: exclusive scan over nseg (<=4096), one block ----------------
__global__ void __launch_bounds__(1024) k_scan(const int* __restrict__ hist, int nseg,
                                               int* __restrict__ ebase, int* __restrict__ cursor) {
    __shared__ int buf[1024];
    int t = threadIdx.x;
    int base = t * 4;
    int a0 = (base + 0 < nseg) ? hist[base + 0] : 0;
    int a1 = (base + 1 < nseg) ? hist[base + 1] : 0;
    int a2 = (base + 2 < nseg) ? hist[base + 2] : 0;
    int a3 = (base + 3 < nseg) ? hist[base + 3] : 0;
    int s = a0 + a1 + a2 + a3;
    buf[t] = s;
    __syncthreads();
    for (int off = 1; off < 1024; off <<= 1) {
        int v = (t >= off) ? buf[t - off] : 0;
        __syncthreads();
        buf[t] += v;
        __syncthreads();
    }
    int e0 = buf[t] - s;
    int e1 = e0 + a0, e2 = e1 + a1, e3 = e2 + a2;
    if (base + 0 < nseg) { ebase[base + 0] = e0; cursor[base + 0] = e0; }
    if (base + 1 < nseg) { ebase[base + 1] = e1; cursor[base + 1] = e1; }
    if (base + 2 < nseg) { ebase[base + 2] = e2; cursor[base + 2] = e2; }
    if (base + 3 < nseg) { ebase[base + 3] = e3; cursor[base + 3] = e3; }
}

// ---------------- K4: scatter edges into per-segment buckets ----------------
__global__ void k_scatter(const unsigned* __restrict__ epack, int E,
                          int* __restrict__ cursor, unsigned short* __restrict__ ebuf) {
    int e = blockIdx.x * blockDim.x + threadIdx.x;
    if (e >= E) return;
    unsigned p = epack[e];
    if (p == 0xFFFFFFFFu) return;
    int pos = atomicAdd(&cursor[p >> 12], 1);
    ebuf[pos] = (unsigned short)(p & 0xFFFu);
}

// ---------------- K5: transpose W1,W2 -> bf16 [fout][fin] ----------------
__global__ void k_wt(const float* __restrict__ W1, const float* __restrict__ W2,
                     short* __restrict__ Wt1, short* __restrict__ Wt2) {
    int n = blockIdx.x, k = threadIdx.x;
    Wt1[n * 128 + k] = (short)f2bf(W1[k * 128 + n]);
    Wt2[n * 128 + k] = (short)f2bf(W2[k * 128 + n]);
}

// ---------------- K6: fused A-build + 2-layer GCN + pool, one wave per segment ----------------
// xt: [feat 128][node 32] bf16, row stride 40 (80B, conflict-free). zb: [node 32][feat 128]
// bf16, XOR-swizzled. Afp (fp32 32x33 + dinv[32]) aliases zb. A itself lives in 8 VGPR (bfr0/1).
__global__ void __launch_bounds__(64, 2) k_gcn3(
    const float* __restrict__ x,
    const int* __restrict__ segstart, const int* __restrict__ segcnt,
    const int* __restrict__ ebase, const int* __restrict__ ecnt,
    const unsigned short* __restrict__ ebuf,
    const short* __restrict__ Wt1, const float* __restrict__ b1,
    const short* __restrict__ Wt2, const float* __restrict__ b2,
    float* __restrict__ pooled)
{
    __shared__ short xt[128 * 40];
    __shared__ float zbF[2048];
    short* zb = (short*)zbF;

    const int seg = blockIdx.x;
    const int l  = threadIdx.x;
    const int fr = l & 15;
    const int g  = l >> 4;
    const int swz = (fr & 7) << 3;

    const int start = segstart[seg];
    const int cnt   = segcnt[seg];

    // ---- 1. issue X loads (global latency overlaps LDS A-build below)
    const int f0 = (l & 7) * 16;
    const int c0 = (l >> 3) * 4;
    float xr[4][16];
    #pragma unroll
    for (int i = 0; i < 4; ++i) {
        if (c0 + i < cnt) {
            const float4* rp = (const float4*)(x + (size_t)(start + c0 + i) * NF + f0);
            float4 a = rp[0], b = rp[1], c = rp[2], d = rp[3];
            xr[i][0]=a.x; xr[i][1]=a.y; xr[i][2]=a.z; xr[i][3]=a.w;
            xr[i][4]=b.x; xr[i][5]=b.y; xr[i][6]=b.z; xr[i][7]=b.w;
            xr[i][8]=c.x; xr[i][9]=c.y; xr[i][10]=c.z; xr[i][11]=c.w;
            xr[i][12]=d.x; xr[i][13]=d.y; xr[i][14]=d.z; xr[i][15]=d.w;
        } else {
            #pragma unroll
            for (int j = 0; j < 16; ++j) xr[i][j] = 0.f;
        }
    }

    // ---- 2. zero Afp (32x33) + dinv (32)
    for (int i = l; i < 1088; i += 64) zbF[i] = 0.f;
    __syncthreads();

    // ---- 3. accumulate edge counts into Afp[dst][src] (LDS atomics)
    {
        int eb = ebase[seg], en = ecnt[seg];
        for (int i = l; i < en; i += 64) {
            unsigned c = ebuf[eb + i];
            if ((c & ((32u << 6) | 32u)) == 0u) {     // dst<32 && src<32
                atomicAdd(&zbF[((c >> 6) & 31) * 33 + (c & 31)], 1.0f);
            }
        }
    }
    __syncthreads();

    // ---- 4. store X transposed into xt (bf16 feat-major)
    #pragma unroll
    for (int j = 0; j < 16; ++j) {
        uint2 w;
        w.x = pk2(xr[0][j], xr[1][j]);
        w.y = pk2(xr[2][j], xr[3][j]);
        *reinterpret_cast<uint2*>(&xt[(f0 + j) * 40 + c0]) = w;
    }

    // ---- 5. deg -> dinv
    {
        int r = l & 31, half = l >> 5;
        float s = 0.f;
        const float* row = &zbF[r * 33 + half * 16];
        #pragma unroll
        for (int k = 0; k < 16; ++k) s += row[k];
        s += __shfl_xor(s, 32);
        float dv = rsqrtf(1.0f + s);
        if (l < 32) zbF[1056 + r] = dv;
    }
    __syncthreads();

    // ---- 6. finalize A into register B-fragments (rows fr and 16+fr, cols g*8..g*8+7)
    bf16x8 bfr0, bfr1;
    {
        float dr0 = zbF[1056 + fr];
        float dr1 = zbF[1056 + 16 + fr];
        float e0[8], e1[8];
        #pragma unroll
        for (int j = 0; j < 8; ++j) {
            int c = g * 8 + j;
            float dc = zbF[1056 + c];
            float v0 = zbF[fr * 33 + c]        * dr0 * dc;
            float v1 = zbF[(16 + fr) * 33 + c] * dr1 * dc;
            if (fr == c)      v0 += dr0 * dr0;
            if (16 + fr == c) v1 += dr1 * dr1;
            e0[j] = v0; e1[j] = v1;
        }
        U8 u0, u1;
        u0.u[0] = pk2(e0[0], e0[1]); u0.u[1] = pk2(e0[2], e0[3]);
        u0.u[2] = pk2(e0[4], e0[5]); u0.u[3] = pk2(e0[6], e0[7]);
        u1.u[0] = pk2(e1[0], e1[1]); u1.u[1] = pk2(e1[2], e1[3]);
        u1.u[2] = pk2(e1[4], e1[5]); u1.u[3] = pk2(e1[6], e1[7]);
        bfr0 = u0.v; bfr1 = u1.v;
    }
    __syncthreads();   // Afp dead; zb region free for Z; xt complete

    // ---- 7. two GCN layers
    for (int layer = 0; layer < 2; ++layer) {
        const short* Wt = layer ? Wt2 : Wt1;
        const float* bb = layer ? b2  : b1;

        // Z-phase: Zt[feat][dst] = mfma(A=Xt-frags, B=A-matrix frags); C cols=dst, rows=feat
        #pragma unroll
        for (int mt = 0; mt < 8; ++mt) {
            bf16x8 af = *(const bf16x8*)&xt[(mt * 16 + fr) * 40 + g * 8];
            f32x4 z0 = {0.f, 0.f, 0.f, 0.f};
            f32x4 z1 = {0.f, 0.f, 0.f, 0.f};
            z0 = __builtin_amdgcn_mfma_f32_16x16x32_bf16(af, bfr0, z0, 0, 0, 0);
            z1 = __builtin_amdgcn_mfma_f32_16x16x32_bf16(af, bfr1, z1, 0, 0, 0);
            int fb = mt * 16 + 4 * g;
            uint2 w0, w1;
            w0.x = pk2(z0[0], z0[1]); w0.y = pk2(z0[2], z0[3]);
            w1.x = pk2(z1[0], z1[1]); w1.y = pk2(z1[2], z1[3]);
            *reinterpret_cast<uint2*>(&zb[fr * 128 + (fb ^ swz)])        = w0;
            *reinterpret_cast<uint2*>(&zb[(16 + fr) * 128 + (fb ^ swz)]) = w1;
        }
        __syncthreads();

        // H-phase: H[node][fout] = relu(Z @ W + b); A=zb rows (node), B=Wt rows (fout)
        f32x4 acc[2][8];
        #pragma unroll
        for (int i = 0; i < 2; ++i)
            #pragma unroll
            for (int j = 0; j < 8; ++j) acc[i][j] = (f32x4){0.f, 0.f, 0.f, 0.f};
        #pragma unroll
        for (int kk = 0; kk < 4; ++kk) {
            int ko = kk * 32 + g * 8;
            bf16x8 a0 = *(const bf16x8*)&zb[fr * 128 + (ko ^ swz)];
            bf16x8 a1 = *(const bf16x8*)&zb[(16 + fr) * 128 + (ko ^ swz)];
            #pragma unroll
            for (int nt = 0; nt < 8; ++nt) {
                bf16x8 wf = *(const bf16x8*)&Wt[(nt * 16 + fr) * 128 + ko];
                acc[0][nt] = __builtin_amdgcn_mfma_f32_16x16x32_bf16(a0, wf, acc[0][nt], 0, 0, 0);
                acc[1][nt] = __builtin_amdgcn_mfma_f32_16x16x32_bf16(a1, wf, acc[1][nt], 0, 0, 0);
            }
        }
        __syncthreads();   // zb reads done (next Z overwrites zb)

        if (layer == 0) {
            // epilogue -> xt (feat-major) for layer 2
            #pragma unroll
            for (int nt = 0; nt < 8; ++nt) {
                float bv = bb[nt * 16 + fr];
                #pragma unroll
                for (int mt = 0; mt < 2; ++mt) {
                    float h0 = acc[mt][nt][0] + bv; h0 = h0 > 0.f ? h0 : 0.f;
                    float h1 = acc[mt][nt][1] + bv; h1 = h1 > 0.f ? h1 : 0.f;
                    float h2 = acc[mt][nt][2] + bv; h2 = h2 > 0.f ? h2 : 0.f;
                    float h3 = acc[mt][nt][3] + bv; h3 = h3 > 0.f ? h3 : 0.f;
                    uint2 w;
                    w.x = pk2(h0, h1); w.y = pk2(h2, h3);
                    *reinterpret_cast<uint2*>(&xt[(nt * 16 + fr) * 40 + mt * 16 + 4 * g]) = w;
                }
            }
        } else {
            // epilogue -> mean pool, fully in registers + shfl
            float rcpc = 1.0f / (float)(cnt > 0 ? cnt : 1);
            #pragma unroll
            for (int nt = 0; nt < 8; ++nt) {
                float bv = bb[nt * 16 + fr];
                float pm = 0.f;
                #pragma unroll
                for (int mt = 0; mt < 2; ++mt)
                    #pragma unroll
                    for (int r = 0; r < 4; ++r) {
                        int node = mt * 16 + 4 * g + r;
                        float h = acc[mt][nt][r] + bv;
                        h = h > 0.f ? h : 0.f;
                        if (node < cnt) pm += h;
                    }
                pm += __shfl_xor(pm, 16);
                pm += __shfl_xor(pm, 32);
                if (l < 16) pooled[(size_t)seg * NF + nt * 16 + l] = pm * rcpc;
            }
        }
        __syncthreads();
    }
}

// ---------------- K7: pair MLP + sigmoid (fp32) ----------------
__global__ void __launch_bounds__(128) k_mlp(
    const float* __restrict__ pooled, const float* __restrict__ Wm1,
    const float* __restrict__ bm1, const float* __restrict__ Wm2,
    const float* __restrict__ bm2, float* __restrict__ out) {
    __shared__ float pr[256];
    __shared__ float partial[2];
    int b = blockIdx.x, t = threadIdx.x;
    pr[t]       = pooled[(size_t)(2 * b) * 128 + t];
    pr[128 + t] = pooled[(size_t)(2 * b + 1) * 128 + t];
    __syncthreads();
    float acc = bm1[t];
    #pragma unroll 4
    for (int k = 0; k < 256; ++k) acc += pr[k] * Wm1[k * 128 + t];
    float h = acc > 0.f ? acc : 0.f;
    float v = h * Wm2[t];
    #pragma unroll
    for (int o = 32; o > 0; o >>= 1) v += __shfl_xor(v, o);
    if ((t & 63) == 0) partial[t >> 6] = v;
    __syncthreads();
    if (t == 0) {
        float z = partial[0] + partial[1] + bm2[0];
        out[b] = 1.f / (1.f + expf(-z));
    }
}

static inline size_t alup(size_t v) { return (v + 255) & ~(size_t)255; }

extern "C" void kernel_launch(void* const* d_in, const int* in_sizes, int n_in,
                              void* d_out, int out_size, void* d_ws, size_t ws_size,
                              hipStream_t stream) {
    const float* x     = (const float*)d_in[0];
    const int*   edge  = (const int*)d_in[1];
    const int*   ptr   = (const int*)d_in[2];
    const int*   split = (const int*)d_in[3];
    const float* W1  = (const float*)d_in[4];
    const float* b1  = (const float*)d_in[5];
    const float* W2  = (const float*)d_in[6];
    const float* b2  = (const float*)d_in[7];
    const float* Wm1 = (const float*)d_in[8];
    const float* bm1 = (const float*)d_in[9];
    const float* Wm2 = (const float*)d_in[10];
    const float* bm2 = (const float*)d_in[11];
    float* out = (float*)d_out;

    const int N    = in_sizes[0] / NF;
    const int E    = in_sizes[1] / 2;
    const int nB   = in_sizes[2] - 1;
    const int nseg = 2 * nB;

    char* ws = (char*)d_ws;
    size_t off = 0;
    unsigned*       segloc   = (unsigned*)(ws + off);       off += alup((size_t)N * 4);
    int*            segstart = (int*)(ws + off);            off += alup((size_t)nseg * 4);
    int*            segcnt   = (int*)(ws + off);            off += alup((size_t)nseg * 4);
    int*            hist     = (int*)(ws + off);            off += alup((size_t)nseg * 4);
    int*            ebase    = (int*)(ws + off);            off += alup((size_t)nseg * 4);
    int*            cursor   = (int*)(ws + off);            off += alup((size_t)nseg * 4);
    unsigned*       epack    = (unsigned*)(ws + off);       off += alup((size_t)E * 4);
    unsigned short* ebuf     = (unsigned short*)(ws + off); off += alup((size_t)E * 2);
    float*          pooled   = (float*)(ws + off);          off += alup((size_t)nseg * NF * 4);
    short*          Wt1      = (short*)(ws + off);          off += alup(128 * 128 * 2);
    short*          Wt2      = (short*)(ws + off);          off += alup(128 * 128 * 2);

    const int* srcp = edge;
    const int* dstp = edge + E;

    hipMemsetAsync(hist, 0, (size_t)nseg * 4, stream);
    k_segtab<<<(nseg + 255) / 256, 256, 0, stream>>>(ptr, split, nseg, segstart, segcnt);
    k_node<<<(N + 255) / 256, 256, 0, stream>>>(ptr, split, nB, N, segloc);
    k_hist<<<(E + 255) / 256, 256, 0, stream>>>(srcp, dstp, E, segloc, epack, hist);
    k_scan<<<1, 1024, 0, stream>>>(hist, nseg, ebase, cursor);
    k_scatter<<<(E + 255) / 256, 256, 0, stream>>>(epack, E, cursor, ebuf);
    k_wt<<<128, 128, 0, stream>>>(W1, W2, Wt1, Wt2);
    k_gcn3<<<nseg, 64, 0, stream>>>(x, segstart, segcnt, ebase, hist, ebuf,
                                    Wt1, b1, Wt2, b2, pooled);
    k_mlp<<<nB, 128, 0, stream>>>(pooled, Wm1, bm1, Wm2, bm2, out);
}

// Round 4
// 246.125 us; speedup vs baseline: 1.4402x; 1.4402x over previous
//
#include <hip/hip_runtime.h>
#include <hip/hip_bf16.h>
#include <math.h>

#define NF 128
#define ECAP 512            // per-segment edge bucket capacity (Poisson(256), 16 sigma headroom)

typedef short bf16x8 __attribute__((ext_vector_type(8)));
typedef float f32x4  __attribute__((ext_vector_type(4)));

union U8 { unsigned u[4]; bf16x8 v; };

__device__ __forceinline__ unsigned pk2(float lo, float hi) {
    union { __hip_bfloat162 h2; unsigned u; } c;
    c.h2 = __float22bfloat162_rn(make_float2(lo, hi));
    return c.u;    // low 16 bits = lo
}
__device__ __forceinline__ unsigned short f2bf(float f) {
    union { __hip_bfloat16 h; unsigned short u; } c;
    c.h = __float2bfloat16(f);
    return c.u;
}

// ---------------- K0: per-segment start/count ----------------
__global__ void k_segtab(const int* __restrict__ ptr, const int* __restrict__ split,
                         int nseg, int* __restrict__ segstart, int* __restrict__ segcnt) {
    int s = blockIdx.x * blockDim.x + threadIdx.x;
    if (s >= nseg) return;
    int g = s >> 1;
    int base = ptr[g];
    int sp = split[g];
    segstart[s] = (s & 1) ? base + sp : base;
    segcnt[s]   = (s & 1) ? (ptr[g + 1] - base - sp) : sp;
}

// ---------------- K1: per-node (seg,loc) ----------------
__global__ void k_node(const int* __restrict__ ptr, const int* __restrict__ split,
                       int nB, int N, unsigned* __restrict__ segloc) {
    int i = blockIdx.x * blockDim.x + threadIdx.x;
    if (i >= N) return;
    int lo = 0, hi = nB + 1;
    while (lo < hi) { int mid = (lo + hi) >> 1; if (ptr[mid] <= i) lo = mid + 1; else hi = mid; }
    int g = lo - 1;
    int local = i - ptr[g];
    int sp = split[g];
    int drug = (local >= sp) ? 1 : 0;
    int seg = 2 * g + drug;
    int loc = local - (drug ? sp : 0);
    segloc[i] = ((unsigned)seg << 8) | (unsigned)loc;
}

// ---------------- K2: block-aggregated counting sort of edges into buckets ----------------
// 64 blocks x 1024 threads. Pass1: LDS histogram over 4096 segments. Reserve runs with one
// global atomic per (block,segment). Pass2: re-read edges, append codes into ebuf buckets.
__global__ void __launch_bounds__(1024) k_sort(
    const int* __restrict__ src, const int* __restrict__ dst, int E, int epb, int nseg,
    const unsigned* __restrict__ segloc, int* __restrict__ cursor,
    unsigned short* __restrict__ ebuf)
{
    __shared__ unsigned cnt[4096];
    __shared__ unsigned gbase[4096];
    const int t  = threadIdx.x;
    const int e0 = blockIdx.x * epb;
    const int e1 = (e0 + epb < E) ? e0 + epb : E;

    for (int i = t; i < 4096; i += 1024) cnt[i] = 0;
    __syncthreads();

    for (int e = e0 + t; e < e1; e += 1024) {
        unsigned ss = segloc[src[e]], dd = segloc[dst[e]];
        if ((ss >> 8) == (dd >> 8)) atomicAdd(&cnt[ss >> 8], 1u);
    }
    __syncthreads();

    for (int i = t; i < nseg; i += 1024) {
        unsigned c = cnt[i];
        if (c) gbase[i] = (unsigned)atomicAdd(&cursor[i], (int)c);
    }
    __syncthreads();
    for (int i = t; i < 4096; i += 1024) cnt[i] = 0;
    __syncthreads();

    for (int e = e0 + t; e < e1; e += 1024) {
        unsigned ss = segloc[src[e]], dd = segloc[dst[e]];
        unsigned seg = ss >> 8;
        if (seg == (dd >> 8)) {
            unsigned pos = gbase[seg] + atomicAdd(&cnt[seg], 1u);
            if (pos < ECAP)
                ebuf[(seg << 9) + pos] = (unsigned short)(((dd & 63u) << 6) | (ss & 63u));
        }
    }
}

// ---------------- K5: transpose W1,W2 -> bf16 [fout][fin] ----------------
__global__ void k_wt(const float* __restrict__ W1, const float* __restrict__ W2,
                     short* __restrict__ Wt1, short* __restrict__ Wt2) {
    int n = blockIdx.x, k = threadIdx.x;
    Wt1[n * 128 + k] = (short)f2bf(W1[k * 128 + n]);
    Wt2[n * 128 + k] = (short)f2bf(W2[k * 128 + n]);
}

// ---------------- K6: fused A-build + 2-layer GCN + pool, one wave per segment ----------------
__global__ void __launch_bounds__(64, 2) k_gcn3(
    const float* __restrict__ x,
    const int* __restrict__ segstart, const int* __restrict__ segcnt,
    const int* __restrict__ ecnt, const unsigned short* __restrict__ ebuf,
    const short* __restrict__ Wt1, const float* __restrict__ b1,
    const short* __restrict__ Wt2, const float* __restrict__ b2,
    float* __restrict__ pooled)
{
    __shared__ short xt[128 * 40];
    __shared__ float zbF[2048];
    short* zb = (short*)zbF;

    const int seg = blockIdx.x;
    const int l  = threadIdx.x;
    const int fr = l & 15;
    const int g  = l >> 4;
    const int swz = (fr & 7) << 3;

    const int start = segstart[seg];
    const int cnt   = segcnt[seg];

    // ---- 1. issue X loads (global latency overlaps LDS A-build below)
    const int f0 = (l & 7) * 16;
    const int c0 = (l >> 3) * 4;
    float xr[4][16];
    #pragma unroll
    for (int i = 0; i < 4; ++i) {
        if (c0 + i < cnt) {
            const float4* rp = (const float4*)(x + (size_t)(start + c0 + i) * NF + f0);
            float4 a = rp[0], b = rp[1], c = rp[2], d = rp[3];
            xr[i][0]=a.x; xr[i][1]=a.y; xr[i][2]=a.z; xr[i][3]=a.w;
            xr[i][4]=b.x; xr[i][5]=b.y; xr[i][6]=b.z; xr[i][7]=b.w;
            xr[i][8]=c.x; xr[i][9]=c.y; xr[i][10]=c.z; xr[i][11]=c.w;
            xr[i][12]=d.x; xr[i][13]=d.y; xr[i][14]=d.z; xr[i][15]=d.w;
        } else {
            #pragma unroll
            for (int j = 0; j < 16; ++j) xr[i][j] = 0.f;
        }
    }

    // ---- 2. zero Afp (32x33) + dinv (32)
    for (int i = l; i < 1088; i += 64) zbF[i] = 0.f;
    __syncthreads();

    // ---- 3. accumulate edge counts into Afp[dst][src] (LDS atomics)
    {
        int en = ecnt[seg];
        en = en < ECAP ? en : ECAP;
        const unsigned short* eb = ebuf + ((size_t)seg << 9);
        for (int i = l; i < en; i += 64) {
            unsigned c = eb[i];
            if ((c & ((32u << 6) | 32u)) == 0u) {
                atomicAdd(&zbF[((c >> 6) & 31) * 33 + (c & 31)], 1.0f);
            }
        }
    }
    __syncthreads();

    // ---- 4. store X transposed into xt (bf16 feat-major)
    #pragma unroll
    for (int j = 0; j < 16; ++j) {
        uint2 w;
        w.x = pk2(xr[0][j], xr[1][j]);
        w.y = pk2(xr[2][j], xr[3][j]);
        *reinterpret_cast<uint2*>(&xt[(f0 + j) * 40 + c0]) = w;
    }

    // ---- 5. deg -> dinv
    {
        int r = l & 31, half = l >> 5;
        float s = 0.f;
        const float* row = &zbF[r * 33 + half * 16];
        #pragma unroll
        for (int k = 0; k < 16; ++k) s += row[k];
        s += __shfl_xor(s, 32);
        float dv = rsqrtf(1.0f + s);
        if (l < 32) zbF[1056 + r] = dv;
    }
    __syncthreads();

    // ---- 6. finalize A into register B-fragments (rows fr and 16+fr, cols g*8..g*8+7)
    bf16x8 bfr0, bfr1;
    {
        float dr0 = zbF[1056 + fr];
        float dr1 = zbF[1056 + 16 + fr];
        float e0[8], e1[8];
        #pragma unroll
        for (int j = 0; j < 8; ++j) {
            int c = g * 8 + j;
            float dc = zbF[1056 + c];
            float v0 = zbF[fr * 33 + c]        * dr0 * dc;
            float v1 = zbF[(16 + fr) * 33 + c] * dr1 * dc;
            if (fr == c)      v0 += dr0 * dr0;
            if (16 + fr == c) v1 += dr1 * dr1;
            e0[j] = v0; e1[j] = v1;
        }
        U8 u0, u1;
        u0.u[0] = pk2(e0[0], e0[1]); u0.u[1] = pk2(e0[2], e0[3]);
        u0.u[2] = pk2(e0[4], e0[5]); u0.u[3] = pk2(e0[6], e0[7]);
        u1.u[0] = pk2(e1[0], e1[1]); u1.u[1] = pk2(e1[2], e1[3]);
        u1.u[2] = pk2(e1[4], e1[5]); u1.u[3] = pk2(e1[6], e1[7]);
        bfr0 = u0.v; bfr1 = u1.v;
    }
    __syncthreads();   // Afp dead; zb region free for Z; xt complete

    // ---- 7. two GCN layers
    for (int layer = 0; layer < 2; ++layer) {
        const short* Wt = layer ? Wt2 : Wt1;
        const float* bb = layer ? b2  : b1;

        // Z-phase: Zt[feat][dst] = mfma(A=Xt-frags, B=A-matrix frags)
        #pragma unroll
        for (int mt = 0; mt < 8; ++mt) {
            bf16x8 af = *(const bf16x8*)&xt[(mt * 16 + fr) * 40 + g * 8];
            f32x4 z0 = {0.f, 0.f, 0.f, 0.f};
            f32x4 z1 = {0.f, 0.f, 0.f, 0.f};
            z0 = __builtin_amdgcn_mfma_f32_16x16x32_bf16(af, bfr0, z0, 0, 0, 0);
            z1 = __builtin_amdgcn_mfma_f32_16x16x32_bf16(af, bfr1, z1, 0, 0, 0);
            int fb = mt * 16 + 4 * g;
            uint2 w0, w1;
            w0.x = pk2(z0[0], z0[1]); w0.y = pk2(z0[2], z0[3]);
            w1.x = pk2(z1[0], z1[1]); w1.y = pk2(z1[2], z1[3]);
            *reinterpret_cast<uint2*>(&zb[fr * 128 + (fb ^ swz)])        = w0;
            *reinterpret_cast<uint2*>(&zb[(16 + fr) * 128 + (fb ^ swz)]) = w1;
        }
        __syncthreads();

        // H-phase: H[node][fout] = relu(Z @ W + b)
        f32x4 acc[2][8];
        #pragma unroll
        for (int i = 0; i < 2; ++i)
            #pragma unroll
            for (int j = 0; j < 8; ++j) acc[i][j] = (f32x4){0.f, 0.f, 0.f, 0.f};
        #pragma unroll
        for (int kk = 0; kk < 4; ++kk) {
            int ko = kk * 32 + g * 8;
            bf16x8 a0 = *(const bf16x8*)&zb[fr * 128 + (ko ^ swz)];
            bf16x8 a1 = *(const bf16x8*)&zb[(16 + fr) * 128 + (ko ^ swz)];
            #pragma unroll
            for (int nt = 0; nt < 8; ++nt) {
                bf16x8 wf = *(const bf16x8*)&Wt[(nt * 16 + fr) * 128 + ko];
                acc[0][nt] = __builtin_amdgcn_mfma_f32_16x16x32_bf16(a0, wf, acc[0][nt], 0, 0, 0);
                acc[1][nt] = __builtin_amdgcn_mfma_f32_16x16x32_bf16(a1, wf, acc[1][nt], 0, 0, 0);
            }
        }
        __syncthreads();   // zb reads done (next Z overwrites zb)

        if (layer == 0) {
            #pragma unroll
            for (int nt = 0; nt < 8; ++nt) {
                float bv = bb[nt * 16 + fr];
                #pragma unroll
                for (int mt = 0; mt < 2; ++mt) {
                    float h0 = acc[mt][nt][0] + bv; h0 = h0 > 0.f ? h0 : 0.f;
                    float h1 = acc[mt][nt][1] + bv; h1 = h1 > 0.f ? h1 : 0.f;
                    float h2 = acc[mt][nt][2] + bv; h2 = h2 > 0.f ? h2 : 0.f;
                    float h3 = acc[mt][nt][3] + bv; h3 = h3 > 0.f ? h3 : 0.f;
                    uint2 w;
                    w.x = pk2(h0, h1); w.y = pk2(h2, h3);
                    *reinterpret_cast<uint2*>(&xt[(nt * 16 + fr) * 40 + mt * 16 + 4 * g]) = w;
                }
            }
        } else {
            // epilogue -> mean pool, fully in registers + shfl
            float rcpc = 1.0f / (float)(cnt > 0 ? cnt : 1);
            #pragma unroll
            for (int nt = 0; nt < 8; ++nt) {
                float bv = bb[nt * 16 + fr];
                float pm = 0.f;
                #pragma unroll
                for (int mt = 0; mt < 2; ++mt)
                    #pragma unroll
                    for (int r = 0; r < 4; ++r) {
                        int node = mt * 16 + 4 * g + r;
                        float h = acc[mt][nt][r] + bv;
                        h = h > 0.f ? h : 0.f;
                        if (node < cnt) pm += h;
                    }
                pm += __shfl_xor(pm, 16);
                pm += __shfl_xor(pm, 32);
                if (l < 16) pooled[(size_t)seg * NF + nt * 16 + l] = pm * rcpc;
            }
        }
        __syncthreads();
    }
}

// ---------------- K7: pair MLP + sigmoid (fp32) ----------------
__global__ void __launch_bounds__(128) k_mlp(
    const float* __restrict__ pooled, const float* __restrict__ Wm1,
    const float* __restrict__ bm1, const float* __restrict__ Wm2,
    const float* __restrict__ bm2, float* __restrict__ out) {
    __shared__ float pr[256];
    __shared__ float partial[2];
    int b = blockIdx.x, t = threadIdx.x;
    pr[t]       = pooled[(size_t)(2 * b) * 128 + t];
    pr[128 + t] = pooled[(size_t)(2 * b + 1) * 128 + t];
    __syncthreads();
    float acc = bm1[t];
    #pragma unroll 4
    for (int k = 0; k < 256; ++k) acc += pr[k] * Wm1[k * 128 + t];
    float h = acc > 0.f ? acc : 0.f;
    float v = h * Wm2[t];
    #pragma unroll
    for (int o = 32; o > 0; o >>= 1) v += __shfl_xor(v, o);
    if ((t & 63) == 0) partial[t >> 6] = v;
    __syncthreads();
    if (t == 0) {
        float z = partial[0] + partial[1] + bm2[0];
        out[b] = 1.f / (1.f + expf(-z));
    }
}

static inline size_t alup(size_t v) { return (v + 255) & ~(size_t)255; }

extern "C" void kernel_launch(void* const* d_in, const int* in_sizes, int n_in,
                              void* d_out, int out_size, void* d_ws, size_t ws_size,
                              hipStream_t stream) {
    const float* x     = (const float*)d_in[0];
    const int*   edge  = (const int*)d_in[1];
    const int*   ptr   = (const int*)d_in[2];
    const int*   split = (const int*)d_in[3];
    const float* W1  = (const float*)d_in[4];
    const float* b1  = (const float*)d_in[5];
    const float* W2  = (const float*)d_in[6];
    const float* b2  = (const float*)d_in[7];
    const float* Wm1 = (const float*)d_in[8];
    const float* bm1 = (const float*)d_in[9];
    const float* Wm2 = (const float*)d_in[10];
    const float* bm2 = (const float*)d_in[11];
    float* out = (float*)d_out;

    const int N    = in_sizes[0] / NF;
    const int E    = in_sizes[1] / 2;
    const int nB   = in_sizes[2] - 1;
    const int nseg = 2 * nB;

    char* ws = (char*)d_ws;
    size_t off = 0;
    unsigned*       segloc   = (unsigned*)(ws + off);       off += alup((size_t)N * 4);
    int*            segstart = (int*)(ws + off);            off += alup((size_t)nseg * 4);
    int*            segcnt   = (int*)(ws + off);            off += alup((size_t)nseg * 4);
    int*            cursor   = (int*)(ws + off);            off += alup((size_t)nseg * 4);
    unsigned short* ebuf     = (unsigned short*)(ws + off); off += alup((size_t)nseg * ECAP * 2);
    float*          pooled   = (float*)(ws + off);          off += alup((size_t)nseg * NF * 4);
    short*          Wt1      = (short*)(ws + off);          off += alup(128 * 128 * 2);
    short*          Wt2      = (short*)(ws + off);          off += alup(128 * 128 * 2);

    const int* srcp = edge;
    const int* dstp = edge + E;

    const int NBLK = 64;
    const int epb  = (E + NBLK - 1) / NBLK;

    hipMemsetAsync(cursor, 0, (size_t)nseg * 4, stream);
    k_segtab<<<(nseg + 255) / 256, 256, 0, stream>>>(ptr, split, nseg, segstart, segcnt);
    k_node<<<(N + 255) / 256, 256, 0, stream>>>(ptr, split, nB, N, segloc);
    k_sort<<<NBLK, 1024, 0, stream>>>(srcp, dstp, E, epb, nseg, segloc, cursor, ebuf);
    k_wt<<<128, 128, 0, stream>>>(W1, W2, Wt1, Wt2);
    k_gcn3<<<nseg, 64, 0, stream>>>(x, segstart, segcnt, cursor, ebuf,
                                    Wt1, b1, Wt2, b2, pooled);
    k_mlp<<<nB, 128, 0, stream>>>(pooled, Wm1, bm1, Wm2, bm2, out);
}

// Round 6
// 222.052 us; speedup vs baseline: 1.5964x; 1.1084x over previous
//
#include <hip/hip_runtime.h>
#include <hip/hip_bf16.h>
#include <math.h>

#define NF 128
#define ECAP 512            // per-segment edge bucket capacity

typedef short bf16x8 __attribute__((ext_vector_type(8)));
typedef float f32x4  __attribute__((ext_vector_type(4)));

union U8 { unsigned u[4]; bf16x8 v; };

__device__ __forceinline__ unsigned pk2(float lo, float hi) {
    union { __hip_bfloat162 h2; unsigned u; } c;
    c.h2 = __float22bfloat162_rn(make_float2(lo, hi));
    return c.u;    // low 16 bits = lo
}
__device__ __forceinline__ unsigned short f2bf(float f) {
    union { __hip_bfloat16 h; unsigned short u; } c;
    c.h = __float2bfloat16(f);
    return c.u;
}

// ---------------- K_prep: segtab + node segloc + W transpose + cursor zero ----------------
__global__ void k_prep(const int* __restrict__ ptr, const int* __restrict__ split,
                       int nB, int N, int nseg,
                       unsigned* __restrict__ segloc, int* __restrict__ segstart,
                       int* __restrict__ segcnt, int* __restrict__ cursor,
                       const float* __restrict__ W1, const float* __restrict__ W2,
                       short* __restrict__ Wt1, short* __restrict__ Wt2) {
    int i = blockIdx.x * blockDim.x + threadIdx.x;
    if (i < N) {
        int lo = 0, hi = nB + 1;
        while (lo < hi) { int mid = (lo + hi) >> 1; if (ptr[mid] <= i) lo = mid + 1; else hi = mid; }
        int g = lo - 1;
        int local = i - ptr[g];
        int sp = split[g];
        int drug = (local >= sp) ? 1 : 0;
        int seg = 2 * g + drug;
        int loc = local - (drug ? sp : 0);
        segloc[i] = ((unsigned)seg << 8) | (unsigned)loc;
    }
    if (i < nseg) {
        int g = i >> 1;
        int base = ptr[g];
        int sp = split[g];
        segstart[i] = (i & 1) ? base + sp : base;
        segcnt[i]   = (i & 1) ? (ptr[g + 1] - base - sp) : sp;
        cursor[i]   = 0;
    }
    if (i < 32768) {
        int m = i >> 14;            // 0 -> W1, 1 -> W2
        int rem = i & 16383;
        int n = rem & 127;          // consecutive lanes -> coalesced read
        int k = rem >> 7;
        const float* W = m ? W2 : W1;
        short* Wt = m ? Wt2 : Wt1;
        Wt[n * 128 + k] = (short)f2bf(W[k * 128 + n]);
    }
}

// ---------------- K_sort: single-pass block-aggregated counting sort ----------------
// 256 blocks x 1024 threads, 4 edges/thread held in registers between phases.
__global__ void __launch_bounds__(1024) k_sort(
    const int* __restrict__ src, const int* __restrict__ dst, int E, int nseg,
    const unsigned* __restrict__ segloc, int* __restrict__ cursor,
    unsigned short* __restrict__ ebuf)
{
    __shared__ unsigned cnt[4096];
    __shared__ unsigned gbase[4096];
    const int t  = threadIdx.x;
    const int e0 = blockIdx.x * 4096;

    for (int i = t; i < 4096; i += 1024) cnt[i] = 0;
    __syncthreads();

    unsigned code[4];
    #pragma unroll
    for (int k = 0; k < 4; ++k) {
        int e = e0 + k * 1024 + t;
        code[k] = 0xFFFFFFFFu;
        if (e < E) {
            unsigned ss = segloc[src[e]], dd = segloc[dst[e]];
            if ((ss >> 8) == (dd >> 8)) {
                code[k] = ((ss >> 8) << 12) | ((dd & 63u) << 6) | (ss & 63u);
                atomicAdd(&cnt[ss >> 8], 1u);
            }
        }
    }
    __syncthreads();

    for (int i = t; i < nseg; i += 1024) {
        unsigned c = cnt[i];
        if (c) gbase[i] = (unsigned)atomicAdd(&cursor[i], (int)c);
    }
    __syncthreads();
    for (int i = t; i < 4096; i += 1024) cnt[i] = 0;
    __syncthreads();

    #pragma unroll
    for (int k = 0; k < 4; ++k) {
        if (code[k] != 0xFFFFFFFFu) {
            unsigned s = code[k] >> 12;
            unsigned pos = gbase[s] + atomicAdd(&cnt[s], 1u);
            if (pos < ECAP)
                ebuf[(s << 9) + pos] = (unsigned short)(code[k] & 0xFFFu);
        }
    }
}

// ---------------- K_gcn5: fused A-build + 2-layer GCN + pool, one wave per segment ----------
// Single 10.25 KB LDS buffer, role-switched with barriers:
//   Afp (A-build scratch) -> xt (X/H feat-major [128][40]) -> zb (Z node-major [32][128], XOR
//   swizzled) -> xt (H1) -> zb (Z2). All transitions stage data in registers first.
__global__ void __launch_bounds__(64, 3) k_gcn5(
    const float* __restrict__ x,
    const int* __restrict__ segstart, const int* __restrict__ segcnt,
    const int* __restrict__ ecnt, const unsigned short* __restrict__ ebuf,
    const short* __restrict__ Wt1, const float* __restrict__ b1,
    const short* __restrict__ Wt2, const float* __restrict__ b2,
    float* __restrict__ pooled)
{
    __shared__ short xt[128 * 40];          // 10.25 KB multi-purpose buffer
    float* Afp = (float*)xt;                // 32x33 counts + 32 dinv (4.35 KB)
    short* zb  = xt;                        // 32x128 bf16 (8 KB), XOR-swizzled

    const int seg = blockIdx.x;
    const int l  = threadIdx.x;
    const int fr = l & 15;
    const int g  = l >> 4;
    const int swz = (fr & 7) << 3;

    const int start = segstart[seg];
    const int cnt   = segcnt[seg];

    // ---- 1. issue X loads into registers (HBM latency hides under A-build)
    const int f0 = (l & 7) * 16;
    const int c0 = (l >> 3) * 4;
    float xr[4][16];
    #pragma unroll
    for (int i = 0; i < 4; ++i) {
        if (c0 + i < cnt) {
            const float4* rp = (const float4*)(x + (size_t)(start + c0 + i) * NF + f0);
            float4 a = rp[0], b = rp[1], c = rp[2], d = rp[3];
            xr[i][0]=a.x; xr[i][1]=a.y; xr[i][2]=a.z; xr[i][3]=a.w;
            xr[i][4]=b.x; xr[i][5]=b.y; xr[i][6]=b.z; xr[i][7]=b.w;
            xr[i][8]=c.x; xr[i][9]=c.y; xr[i][10]=c.z; xr[i][11]=c.w;
            xr[i][12]=d.x; xr[i][13]=d.y; xr[i][14]=d.z; xr[i][15]=d.w;
        } else {
            #pragma unroll
            for (int j = 0; j < 16; ++j) xr[i][j] = 0.f;
        }
    }

    // ---- 2. zero Afp (32x33 + 32 dinv)
    for (int i = l; i < 1088; i += 64) Afp[i] = 0.f;
    __syncthreads();

    // ---- 3. edge counts into Afp[dst][src] (LDS atomics)
    {
        int en = ecnt[seg];
        en = en < ECAP ? en : ECAP;
        const unsigned short* eb = ebuf + ((size_t)seg << 9);
        for (int i = l; i < en; i += 64) {
            unsigned c = eb[i];
            if ((c & ((32u << 6) | 32u)) == 0u)
                atomicAdd(&Afp[((c >> 6) & 31) * 33 + (c & 31)], 1.0f);
        }
    }
    __syncthreads();

    // ---- 4. deg -> dinv
    {
        int r = l & 31, half = l >> 5;
        float s = 0.f;
        const float* row = &Afp[r * 33 + half * 16];
        #pragma unroll
        for (int k = 0; k < 16; ++k) s += row[k];
        s += __shfl_xor(s, 32);
        float dv = rsqrtf(1.0f + s);
        if (l < 32) Afp[1056 + r] = dv;
    }
    __syncthreads();

    // ---- 5. finalize A into register B-fragments (rows fr, 16+fr; cols g*8..+7)
    bf16x8 bfr0, bfr1;
    {
        float dr0 = Afp[1056 + fr];
        float dr1 = Afp[1056 + 16 + fr];
        float e0[8], e1[8];
        #pragma unroll
        for (int j = 0; j < 8; ++j) {
            int c = g * 8 + j;
            float dc = Afp[1056 + c];
            float v0 = Afp[fr * 33 + c]        * dr0 * dc;
            float v1 = Afp[(16 + fr) * 33 + c] * dr1 * dc;
            if (fr == c)      v0 += dr0 * dr0;
            if (16 + fr == c) v1 += dr1 * dr1;
            e0[j] = v0; e1[j] = v1;
        }
        U8 u0, u1;
        u0.u[0] = pk2(e0[0], e0[1]); u0.u[1] = pk2(e0[2], e0[3]);
        u0.u[2] = pk2(e0[4], e0[5]); u0.u[3] = pk2(e0[6], e0[7]);
        u1.u[0] = pk2(e1[0], e1[1]); u1.u[1] = pk2(e1[2], e1[3]);
        u1.u[2] = pk2(e1[4], e1[5]); u1.u[3] = pk2(e1[6], e1[7]);
        bfr0 = u0.v; bfr1 = u1.v;
    }
    __syncthreads();          // Afp dead; buffer becomes xt

    // ---- 6. store X transposed into xt (bf16 feat-major, stride 40)
    #pragma unroll
    for (int j = 0; j < 16; ++j) {
        uint2 w;
        w.x = pk2(xr[0][j], xr[1][j]);
        w.y = pk2(xr[2][j], xr[3][j]);
        *reinterpret_cast<uint2*>(&xt[(f0 + j) * 40 + c0]) = w;
    }
    __syncthreads();

    // ---- 7. two GCN layers
    for (int layer = 0; layer < 2; ++layer) {
        const short* Wt = layer ? Wt2 : Wt1;
        const float* bb = layer ? b2  : b1;

        // Z-phase: Zt[feat][node] into registers (zp, static indexing only)
        unsigned zp[8][4];
        __builtin_amdgcn_s_setprio(1);
        #pragma unroll
        for (int mt = 0; mt < 8; ++mt) {
            bf16x8 af = *(const bf16x8*)&xt[(mt * 16 + fr) * 40 + g * 8];
            f32x4 z0 = {0.f, 0.f, 0.f, 0.f};
            f32x4 z1 = {0.f, 0.f, 0.f, 0.f};
            z0 = __builtin_amdgcn_mfma_f32_16x16x32_bf16(af, bfr0, z0, 0, 0, 0);
            z1 = __builtin_amdgcn_mfma_f32_16x16x32_bf16(af, bfr1, z1, 0, 0, 0);
            zp[mt][0] = pk2(z0[0], z0[1]); zp[mt][1] = pk2(z0[2], z0[3]);
            zp[mt][2] = pk2(z1[0], z1[1]); zp[mt][3] = pk2(z1[2], z1[3]);
        }
        __builtin_amdgcn_s_setprio(0);
        __syncthreads();    // all xt reads retired; buffer becomes zb

        // write Z to zb: node-major [32][128], XOR-swizzled (round-4-proven mapping)
        #pragma unroll
        for (int mt = 0; mt < 8; ++mt) {
            int fb = mt * 16 + 4 * g;
            uint2 w0, w1;
            w0.x = zp[mt][0]; w0.y = zp[mt][1];
            w1.x = zp[mt][2]; w1.y = zp[mt][3];
            *reinterpret_cast<uint2*>(&zb[fr * 128 + (fb ^ swz)])        = w0;
            *reinterpret_cast<uint2*>(&zb[(16 + fr) * 128 + (fb ^ swz)]) = w1;
        }
        __syncthreads();

        // H-phase: H[node][fout] = relu(Z @ W + b)
        f32x4 acc[2][8];
        #pragma unroll
        for (int i = 0; i < 2; ++i)
            #pragma unroll
            for (int j = 0; j < 8; ++j) acc[i][j] = (f32x4){0.f, 0.f, 0.f, 0.f};
        #pragma unroll
        for (int kk = 0; kk < 4; ++kk) {
            const int ko = kk * 32 + g * 8;
            bf16x8 a0 = *(const bf16x8*)&zb[fr * 128 + (ko ^ swz)];
            bf16x8 a1 = *(const bf16x8*)&zb[(16 + fr) * 128 + (ko ^ swz)];
            __builtin_amdgcn_s_setprio(1);
            #pragma unroll
            for (int nt = 0; nt < 8; ++nt) {
                bf16x8 wf = *(const bf16x8*)&Wt[(nt * 16 + fr) * 128 + ko];
                acc[0][nt] = __builtin_amdgcn_mfma_f32_16x16x32_bf16(a0, wf, acc[0][nt], 0, 0, 0);
                acc[1][nt] = __builtin_amdgcn_mfma_f32_16x16x32_bf16(a1, wf, acc[1][nt], 0, 0, 0);
            }
            __builtin_amdgcn_s_setprio(0);
        }

        if (layer == 0) {
            __syncthreads();    // zb reads retired; buffer becomes xt (H1)
            #pragma unroll
            for (int nt = 0; nt < 8; ++nt) {
                float bv = bb[nt * 16 + fr];
                #pragma unroll
                for (int mt = 0; mt < 2; ++mt) {
                    float h0 = acc[mt][nt][0] + bv; h0 = h0 > 0.f ? h0 : 0.f;
                    float h1 = acc[mt][nt][1] + bv; h1 = h1 > 0.f ? h1 : 0.f;
                    float h2 = acc[mt][nt][2] + bv; h2 = h2 > 0.f ? h2 : 0.f;
                    float h3 = acc[mt][nt][3] + bv; h3 = h3 > 0.f ? h3 : 0.f;
                    uint2 w;
                    w.x = pk2(h0, h1); w.y = pk2(h2, h3);
                    *reinterpret_cast<uint2*>(&xt[(nt * 16 + fr) * 40 + mt * 16 + 4 * g]) = w;
                }
            }
            __syncthreads();
        } else {
            // mean pool in registers + shfl
            float rcpc = 1.0f / (float)(cnt > 0 ? cnt : 1);
            #pragma unroll
            for (int nt = 0; nt < 8; ++nt) {
                float bv = bb[nt * 16 + fr];
                float pm = 0.f;
                #pragma unroll
                for (int mt = 0; mt < 2; ++mt)
                    #pragma unroll
                    for (int r = 0; r < 4; ++r) {
                        int node = mt * 16 + 4 * g + r;
                        float h = acc[mt][nt][r] + bv;
                        h = h > 0.f ? h : 0.f;
                        if (node < cnt) pm += h;
                    }
                pm += __shfl_xor(pm, 16);
                pm += __shfl_xor(pm, 32);
                if (l < 16) pooled[(size_t)seg * NF + nt * 16 + l] = pm * rcpc;
            }
        }
    }
}

// ---------------- K_mlp: pair MLP + sigmoid, 4 pairs per block ----------------
__global__ void __launch_bounds__(128) k_mlp(
    const float* __restrict__ pooled, const float* __restrict__ Wm1,
    const float* __restrict__ bm1, const float* __restrict__ Wm2,
    const float* __restrict__ bm2, float* __restrict__ out, int nB) {
    __shared__ float pr[4][256];
    __shared__ float red[4][2];
    const int b0 = blockIdx.x * 4;
    const int t = threadIdx.x;

    for (int i = t; i < 1024; i += 128) {
        int p = i >> 8, c = i & 255;
        int pair = b0 + p;
        pr[p][c] = (pair < nB) ? pooled[(size_t)(2 * pair + (c >> 7)) * 128 + (c & 127)] : 0.f;
    }
    __syncthreads();

    float acc0 = bm1[t], acc1 = acc0, acc2 = acc0, acc3 = acc0;
    #pragma unroll 4
    for (int k = 0; k < 256; ++k) {
        float w = Wm1[k * 128 + t];
        acc0 += pr[0][k] * w;
        acc1 += pr[1][k] * w;
        acc2 += pr[2][k] * w;
        acc3 += pr[3][k] * w;
    }
    float wm2 = Wm2[t];
    float v[4];
    v[0] = (acc0 > 0.f ? acc0 : 0.f) * wm2;
    v[1] = (acc1 > 0.f ? acc1 : 0.f) * wm2;
    v[2] = (acc2 > 0.f ? acc2 : 0.f) * wm2;
    v[3] = (acc3 > 0.f ? acc3 : 0.f) * wm2;
    #pragma unroll
    for (int p = 0; p < 4; ++p) {
        #pragma unroll
        for (int o = 32; o > 0; o >>= 1) v[p] += __shfl_xor(v[p], o);
    }
    if ((t & 63) == 0) {
        int w = t >> 6;
        red[0][w] = v[0]; red[1][w] = v[1]; red[2][w] = v[2]; red[3][w] = v[3];
    }
    __syncthreads();
    if (t < 4 && b0 + t < nB) {
        float z = red[t][0] + red[t][1] + bm2[0];
        out[b0 + t] = 1.f / (1.f + expf(-z));
    }
}

static inline size_t alup(size_t v) { return (v + 255) & ~(size_t)255; }

extern "C" void kernel_launch(void* const* d_in, const int* in_sizes, int n_in,
                              void* d_out, int out_size, void* d_ws, size_t ws_size,
                              hipStream_t stream) {
    const float* x     = (const float*)d_in[0];
    const int*   edge  = (const int*)d_in[1];
    const int*   ptr   = (const int*)d_in[2];
    const int*   split = (const int*)d_in[3];
    const float* W1  = (const float*)d_in[4];
    const float* b1  = (const float*)d_in[5];
    const float* W2  = (const float*)d_in[6];
    const float* b2  = (const float*)d_in[7];
    const float* Wm1 = (const float*)d_in[8];
    const float* bm1 = (const float*)d_in[9];
    const float* Wm2 = (const float*)d_in[10];
    const float* bm2 = (const float*)d_in[11];
    float* out = (float*)d_out;

    const int N    = in_sizes[0] / NF;
    const int E    = in_sizes[1] / 2;
    const int nB   = in_sizes[2] - 1;
    const int nseg = 2 * nB;

    char* ws = (char*)d_ws;
    size_t off = 0;
    unsigned*       segloc   = (unsigned*)(ws + off);       off += alup((size_t)N * 4);
    int*            segstart = (int*)(ws + off);            off += alup((size_t)nseg * 4);
    int*            segcnt   = (int*)(ws + off);            off += alup((size_t)nseg * 4);
    int*            cursor   = (int*)(ws + off);            off += alup((size_t)nseg * 4);
    unsigned short* ebuf     = (unsigned short*)(ws + off); off += alup((size_t)nseg * ECAP * 2);
    float*          pooled   = (float*)(ws + off);          off += alup((size_t)nseg * NF * 4);
    short*          Wt1      = (short*)(ws + off);          off += alup(128 * 128 * 2);
    short*          Wt2      = (short*)(ws + off);          off += alup(128 * 128 * 2);

    const int* srcp = edge;
    const int* dstp = edge + E;

    int prepN = N > 32768 ? N : 32768;
    if (prepN < nseg) prepN = nseg;

    k_prep<<<(prepN + 255) / 256, 256, 0, stream>>>(ptr, split, nB, N, nseg,
                                                    segloc, segstart, segcnt, cursor,
                                                    W1, W2, Wt1, Wt2);
    k_sort<<<(E + 4095) / 4096, 1024, 0, stream>>>(srcp, dstp, E, nseg, segloc, cursor, ebuf);
    k_gcn5<<<nseg, 64, 0, stream>>>(x, segstart, segcnt, cursor, ebuf,
                                    Wt1, b1, Wt2, b2, pooled);
    k_mlp<<<(nB + 3) / 4, 128, 0, stream>>>(pooled, Wm1, bm1, Wm2, bm2, out, nB);
}